// Round 1
// baseline (104.309 us; speedup 1.0000x reference)
//
#include <hip/hip_runtime.h>
#include <hip/hip_bf16.h>

// LengthRegulator: x (B,S,D) f32, durations (B,S) int.
// dur = clip(dur,1,None); cum = cumsum(dur, axis=1); totals = cum[:,-1];
// out[b,p,:] = x[b, searchsorted_right(cum[b], p) clipped to S-1, :] for p < totals[b], else 0.
// Output shape (B, max_len, D) with max_len = out_size/(B*D).

constexpr int B = 32;
constexpr int S = 1024;
constexpr int D = 512;

// ---------------- Kernel A: per-batch inclusive scan of clipped durations ----
__global__ void lr_scan_kernel(const int* __restrict__ durations,
                               int* __restrict__ cum) {
    __shared__ int buf[S];
    const int b = blockIdx.x;
    const int t = threadIdx.x;

    int d = durations[b * S + t];
    if (d < 1) d = 1;
    buf[t] = d;
    __syncthreads();

    // Hillis-Steele inclusive scan over S=1024 elements.
    #pragma unroll
    for (int off = 1; off < S; off <<= 1) {
        int v = (t >= off) ? buf[t - off] : 0;
        __syncthreads();
        buf[t] += v;
        __syncthreads();
    }

    cum[b * S + t] = buf[t];
}

// ---------------- Kernel B: gather + mask ------------------------------------
// One block (128 threads) per output row (b, p). Lane 0 binary-searches cum[b]
// for the source index; block copies the 512-float row as float4 (2048 B).
__global__ void lr_gather_kernel(const float* __restrict__ x,
                                 const int* __restrict__ cum,
                                 float4* __restrict__ out,
                                 int max_len) {
    const int row = blockIdx.x;           // 0 .. B*max_len-1
    const int b = row / max_len;
    const int p = row - b * max_len;

    const int* __restrict__ c = cum + b * S;

    __shared__ int s_idx;
    if (threadIdx.x == 0) {
        const int total = c[S - 1];
        if (p >= total) {
            s_idx = -1;                    // masked tail -> zeros
        } else {
            // searchsorted(c, p, side='right'): first i with c[i] > p
            int lo = 0, hi = S;
            while (lo < hi) {
                const int mid = (lo + hi) >> 1;
                if (c[mid] <= p) lo = mid + 1; else hi = mid;
            }
            s_idx = lo < (S - 1) ? lo : (S - 1);
        }
    }
    __syncthreads();

    const int idx = s_idx;
    float4 v = make_float4(0.f, 0.f, 0.f, 0.f);
    if (idx >= 0) {
        const float4* src = reinterpret_cast<const float4*>(
            x + ((size_t)b * S + idx) * D);
        v = src[threadIdx.x];
    }
    out[(size_t)row * (D / 4) + threadIdx.x] = v;
}

extern "C" void kernel_launch(void* const* d_in, const int* in_sizes, int n_in,
                              void* d_out, int out_size, void* d_ws, size_t ws_size,
                              hipStream_t stream) {
    const float* x = (const float*)d_in[0];
    const int* durations = (const int*)d_in[1];
    float* out = (float*)d_out;

    int* cum = (int*)d_ws;                // B*S*4 = 128 KB scratch

    const int max_len = out_size / (B * D);

    lr_scan_kernel<<<B, S, 0, stream>>>(durations, cum);

    const int n_rows = B * max_len;
    lr_gather_kernel<<<n_rows, D / 4, 0, stream>>>(
        x, cum, (float4*)out, max_len);
}

// Round 2
// 84.090 us; speedup vs baseline: 1.2404x; 1.2404x over previous
//
#include <hip/hip_runtime.h>
#include <hip/hip_bf16.h>

// LengthRegulator: x (B,S,D) f32, durations (B,S) int.
// dur = clip(dur,1,None); cum = cumsum(dur, axis=1); totals = cum[:,-1];
// out[b,p,:] = x[b, searchsorted_right(cum[b], p) clipped S-1, :] for p < totals[b], else 0.
// Output (B, max_len, D), max_len = out_size/(B*D).

constexpr int B = 32;
constexpr int S = 1024;
constexpr int D = 512;
constexpr int VEC_PER_ROW = D / 4;   // 128 float4 per output row

// ---- Kernel A: per-batch scan + scatter absolute source-row index ----------
// idx_map[b*max_len + p] = b*S + s  for cum[s-1] <= p < cum[s]; -1 in the tail.
__global__ void lr_scan_scatter(const int* __restrict__ durations,
                                int* __restrict__ idx_map,
                                int max_len) {
    __shared__ int buf[S];
    const int b = blockIdx.x;
    const int t = threadIdx.x;

    int d = durations[b * S + t];
    if (d < 1) d = 1;
    buf[t] = d;
    __syncthreads();

    // Hillis-Steele inclusive scan (S=1024).
    #pragma unroll
    for (int off = 1; off < S; off <<= 1) {
        int v = (t >= off) ? buf[t - off] : 0;
        __syncthreads();
        buf[t] += v;
        __syncthreads();
    }

    const int end   = buf[t];        // inclusive cumsum at t
    const int start = end - d;       // exclusive
    int* __restrict__ m = idx_map + b * max_len;
    const int src = b * S + t;       // absolute source row
    for (int p = start; p < end; ++p) m[p] = src;

    // zero-mask tail: positions [total, max_len) -> -1
    const int total = buf[S - 1];
    for (int p = total + t; p < max_len; p += S) m[p] = -1;
}

// ---- Kernel B: branch-free streaming gather --------------------------------
// One thread per float4 of output. idx load is wave-uniform (128 vec/row).
__global__ void lr_gather(const float4* __restrict__ x4,
                          const int* __restrict__ idx_map,
                          float4* __restrict__ out,
                          int total_vec) {
    const int gid = blockIdx.x * blockDim.x + threadIdx.x;
    if (gid >= total_vec) return;

    const int row  = gid >> 7;            // / VEC_PER_ROW
    const int lane = gid & (VEC_PER_ROW - 1);
    const int idx  = idx_map[row];        // absolute source row or -1

    float4 v = make_float4(0.f, 0.f, 0.f, 0.f);
    if (idx >= 0) v = x4[(size_t)idx * VEC_PER_ROW + lane];
    out[gid] = v;
}

extern "C" void kernel_launch(void* const* d_in, const int* in_sizes, int n_in,
                              void* d_out, int out_size, void* d_ws, size_t ws_size,
                              hipStream_t stream) {
    const float* x = (const float*)d_in[0];
    const int* durations = (const int*)d_in[1];
    float* out = (float*)d_out;

    int* idx_map = (int*)d_ws;            // B*max_len*4 bytes (~0.5 MB)

    const int max_len = out_size / (B * D);

    lr_scan_scatter<<<B, S, 0, stream>>>(durations, idx_map, max_len);

    const int total_vec = out_size / 4;   // number of float4s in out
    const int block = 256;
    const int grid = (total_vec + block - 1) / block;
    lr_gather<<<grid, block, 0, stream>>>(
        (const float4*)x, idx_map, (float4*)out, total_vec);
}

// Round 3
// 61.351 us; speedup vs baseline: 1.7002x; 1.3706x over previous
//
#include <hip/hip_runtime.h>
#include <hip/hip_bf16.h>

// LengthRegulator: x (B,S,D) f32, durations (B,S) int.
// dur = clip(dur,1,None); cum = cumsum(dur, axis=1); totals = cum[:,-1];
// out[b,p,:] = x[b, searchsorted_right(cum[b], p) clipped S-1, :] for p < totals[b], else 0.
// Output (B, max_len, D), max_len = out_size/(B*D).

constexpr int B = 32;
constexpr int S = 1024;
constexpr int D = 512;
constexpr int VEC_PER_ROW = D / 4;       // 128 float4 per row

using f4 = __attribute__((ext_vector_type(4))) float;

// ---- Kernel A: per-batch scan (wave-scan, 4 elems/thread) + scatter --------
// idx_map[b*max_len + p] = absolute source row (b*S+s), or -1 in masked tail.
__global__ void lr_scan_scatter(const int* __restrict__ durations,
                                int* __restrict__ idx_map,
                                int max_len) {
    const int b    = blockIdx.x;
    const int t    = threadIdx.x;        // 0..255
    const int lane = t & 63;
    const int wv   = t >> 6;             // wave id 0..3

    // 4 durations per thread (16B vector load)
    int4 d4 = reinterpret_cast<const int4*>(durations + b * S)[t];
    const int d0 = d4.x < 1 ? 1 : d4.x;
    const int d1 = d4.y < 1 ? 1 : d4.y;
    const int d2 = d4.z < 1 ? 1 : d4.z;
    const int d3 = d4.w < 1 ? 1 : d4.w;
    const int tsum = d0 + d1 + d2 + d3;

    // inclusive wave scan of per-thread sums
    int inc = tsum;
    #pragma unroll
    for (int off = 1; off < 64; off <<= 1) {
        int n = __shfl_up(inc, off, 64);
        if (lane >= off) inc += n;
    }

    __shared__ int wsum[4];
    if (lane == 63) wsum[wv] = inc;
    __syncthreads();

    int base = 0;
    #pragma unroll
    for (int j = 0; j < 4; ++j) if (j < wv) base += wsum[j];
    const int blockTotal = wsum[0] + wsum[1] + wsum[2] + wsum[3];

    // exclusive prefix for this thread's first element
    int p = base + inc - tsum;
    int* __restrict__ m = idx_map + b * max_len;
    int src = b * S + t * 4;

    for (int k = 0; k < d0; ++k) m[p++] = src;
    ++src;
    for (int k = 0; k < d1; ++k) m[p++] = src;
    ++src;
    for (int k = 0; k < d2; ++k) m[p++] = src;
    ++src;
    for (int k = 0; k < d3; ++k) m[p++] = src;

    // masked tail -> -1
    for (int q = blockTotal + t; q < max_len; q += 256) m[q] = -1;
}

// ---- Kernel B: streaming gather, one wave per output row -------------------
// Lane handles float4 #lane and #(lane+64). idx is wave-uniform -> SGPR.
// Nontemporal stores keep x resident in L2/L3.
__global__ void lr_gather(const f4* __restrict__ x4,
                          const int* __restrict__ idx_map,
                          f4* __restrict__ out,
                          int n_rows) {
    const int row = blockIdx.x * 4 + (threadIdx.x >> 6);
    if (row >= n_rows) return;
    const int lane = threadIdx.x & 63;

    int idx = idx_map[row];                       // same for all 64 lanes
    idx = __builtin_amdgcn_readfirstlane(idx);    // hoist to SGPR

    f4 a = {0.f, 0.f, 0.f, 0.f};
    f4 c = {0.f, 0.f, 0.f, 0.f};
    if (idx >= 0) {
        const f4* __restrict__ src = x4 + (size_t)idx * VEC_PER_ROW;
        a = src[lane];
        c = src[lane + 64];
    }
    f4* __restrict__ dst = out + (size_t)row * VEC_PER_ROW;
    __builtin_nontemporal_store(a, dst + lane);
    __builtin_nontemporal_store(c, dst + lane + 64);
}

extern "C" void kernel_launch(void* const* d_in, const int* in_sizes, int n_in,
                              void* d_out, int out_size, void* d_ws, size_t ws_size,
                              hipStream_t stream) {
    const float* x = (const float*)d_in[0];
    const int* durations = (const int*)d_in[1];
    float* out = (float*)d_out;

    int* idx_map = (int*)d_ws;                    // B*max_len*4 bytes (<1 MB)

    const int max_len = out_size / (B * D);

    lr_scan_scatter<<<B, 256, 0, stream>>>(durations, idx_map, max_len);

    const int n_rows = out_size / D;              // B * max_len
    const int grid = (n_rows + 3) / 4;            // 4 rows (waves) per block
    lr_gather<<<grid, 256, 0, stream>>>(
        (const f4*)x, idx_map, (f4*)out, n_rows);
}